// Round 2
// baseline (245.952 us; speedup 1.0000x reference)
//
#include <hip/hip_runtime.h>

// radius_graph dense mask: out[i,j] = (||pos_i - pos_j||^2 <= 9.0) ? 1 : 0  (int32!)
// The harness reads the output as int32 (bool reference). Round-0 failure was
// writing 1.0f (0x3F800000) -> read as 1065353216.
//
// Rounding model matched to the numpy/BLAS reference:
//   sq   = (x*x + y*y) + z*z                  rounded per op (np.sum, 3 elems)
//   dot  = fma(z,z', fma(y,y', x*x'))         BLAS sgemm FMA accumulation
//   d2   = (sq_i + sq_j) - 2*dot              2*dot exact; adds/sub rounded
//   mask = max(d2,0) <= 9.0f

#define NPTS 8192
#define R2 9.0f

__global__ __launch_bounds__(256) void radius_mask_kernel(
    const float* __restrict__ pos, int* __restrict__ out) {
    const int i = blockIdx.y;                              // row (uniform per block)
    const int j0 = (blockIdx.x * 256 + threadIdx.x) * 4;   // 4 cols per thread

    // row position: block-uniform -> scalar loads
    const float xi = pos[i * 3 + 0];
    const float yi = pos[i * 3 + 1];
    const float zi = pos[i * 3 + 2];
    const float sqi = __fadd_rn(__fadd_rn(__fmul_rn(xi, xi), __fmul_rn(yi, yi)),
                                __fmul_rn(zi, zi));

    // 4 consecutive positions = 48 B, 16B-aligned (j0 % 4 == 0 -> byte off 48*t)
    const float4* p4 = reinterpret_cast<const float4*>(pos + (size_t)j0 * 3);
    const float4 a = p4[0];
    const float4 b = p4[1];
    const float4 c = p4[2];
    const float xj[4] = {a.x, a.w, b.z, c.y};
    const float yj[4] = {a.y, b.x, b.w, c.z};
    const float zj[4] = {a.z, b.y, c.x, c.w};

    int4 res;
    int* r = reinterpret_cast<int*>(&res);
#pragma unroll
    for (int k = 0; k < 4; ++k) {
        const float sqj = __fadd_rn(
            __fadd_rn(__fmul_rn(xj[k], xj[k]), __fmul_rn(yj[k], yj[k])),
            __fmul_rn(zj[k], zj[k]));
        // BLAS-style FMA accumulation: ((x*x') fma y*y') fma z*z'
        const float dot = __fmaf_rn(zi, zj[k],
                           __fmaf_rn(yi, yj[k], __fmul_rn(xi, xj[k])));
        const float s = __fadd_rn(sqi, sqj);
        float d2 = __fsub_rn(s, __fmul_rn(2.0f, dot));
        d2 = fmaxf(d2, 0.0f);
        r[k] = (d2 <= R2) ? 1 : 0;
    }

    reinterpret_cast<int4*>(out)[((size_t)i * NPTS + j0) >> 2] = res;
}

extern "C" void kernel_launch(void* const* d_in, const int* in_sizes, int n_in,
                              void* d_out, int out_size, void* d_ws, size_t ws_size,
                              hipStream_t stream) {
    const float* pos = (const float*)d_in[0];
    int* out = (int*)d_out;

    // 8192 cols / (256 threads * 4 cols) = 8 blocks in x; 8192 rows in y
    dim3 grid(NPTS / (256 * 4), NPTS, 1);
    dim3 block(256, 1, 1);
    radius_mask_kernel<<<grid, block, 0, stream>>>(pos, out);
}